// Round 9
// baseline (442.246 us; speedup 1.0000x reference)
//
#include <hip/hip_runtime.h>
#include <hip/hip_bf16.h>
#include <math.h>

// Problem constants (from reference)
#define T_TOK 8192            // B*S = 4*2048
#define HID   1024
#define NE    8
#define TOPKN 2
#define INTER 1408
#define NROWS (T_TOK*TOPKN)   // 16384 routed (token,expert) rows
#define MAXWL256 72           // max 256-row worklist entries (gemm1)
#define MAXWL64  264          // max 64-row worklist entries (gemm2)
#define RBLK  256             // router blocks (32 tokens each)
#define GX1   (INTER/128)     // gemm1 grid.x = 11
#define GX2   (HID/128)       // gemm2 grid.x = 8
#define NTRT  8448            // transpose tiles: 24 (m,e) x 352

typedef __attribute__((ext_vector_type(8))) __bf16 bf16x8;
typedef __attribute__((ext_vector_type(4))) float f32x4;
typedef __attribute__((ext_vector_type(4))) unsigned int u32x4;

__device__ __forceinline__ unsigned short f2bf(float f) {
    unsigned int u = __builtin_bit_cast(unsigned int, f);
    unsigned int lsb = (u >> 16) & 1u;
    u += 0x7fffu + lsb;            // round-to-nearest-even
    return (unsigned short)(u >> 16);
}

// async global->LDS, 16B per lane (m97 pattern).
__device__ __forceinline__ void gl2lds16(const void* g, void* l) {
    __builtin_amdgcn_global_load_lds(
        (const __attribute__((address_space(1))) unsigned int*)g,
        (__attribute__((address_space(3))) unsigned int*)l, 16, 0, 0);
}

// ---------------------------------------------------------------- pre (router + weight transpose, fused)
__global__ __launch_bounds__(256) void moe_pre(
    const float* __restrict__ x, const float* __restrict__ gate_w,
    const float* __restrict__ w_gate, const float* __restrict__ w_up,
    const float* __restrict__ w_down,
    unsigned short* __restrict__ xb, float* __restrict__ logits_out,
    int* __restrict__ topk_idx, float* __restrict__ topk_w,
    int* __restrict__ hist_g,
    unsigned short* __restrict__ wg_t, unsigned short* __restrict__ wu_t,
    unsigned short* __restrict__ wd_t)
{
    __shared__ float smem[64 * 65];
    int tid = threadIdx.x;

    if ((int)blockIdx.x < RBLK) {
        // ---------------- router body ----------------
        int* lh = (int*)smem;
        int wave = tid >> 6, lane = tid & 63;
        if (tid < NE) lh[tid] = 0;
        __syncthreads();
#pragma unroll 1
        for (int i = 0; i < 8; i++) {
            int t = blockIdx.x * 32 + wave * 8 + i;
            const float4* xr = (const float4*)(x + (size_t)t * HID);
            float acc[NE];
#pragma unroll
            for (int e = 0; e < NE; e++) acc[e] = 0.f;
#pragma unroll
            for (int j = 0; j < 4; j++) {
                float4 xv = xr[j * 64 + lane];
                ushort4 pk;
                pk.x = f2bf(xv.x); pk.y = f2bf(xv.y);
                pk.z = f2bf(xv.z); pk.w = f2bf(xv.w);
                *(ushort4*)(xb + (size_t)t * HID + j * 256 + lane * 4) = pk;
#pragma unroll
                for (int e = 0; e < NE; e++) {
                    float4 gv = *(const float4*)(gate_w + e * HID + j * 256 + lane * 4);
                    acc[e] += xv.x * gv.x + xv.y * gv.y + xv.z * gv.z + xv.w * gv.w;
                }
            }
#pragma unroll
            for (int e = 0; e < NE; e++) {
                float v = acc[e];
#pragma unroll
                for (int off = 32; off; off >>= 1) v += __shfl_xor(v, off, 64);
                acc[e] = v;
            }
            if (lane == 0) {
                float m = acc[0];
#pragma unroll
                for (int e = 1; e < NE; e++) m = fmaxf(m, acc[e]);
                float p[NE]; float s = 0.f;
#pragma unroll
                for (int e = 0; e < NE; e++) { p[e] = expf(acc[e] - m); s += p[e]; }
                float inv = 1.f / s;
#pragma unroll
                for (int e = 0; e < NE; e++) logits_out[(size_t)t * NE + e] = acc[e];
                int i0 = 0;
#pragma unroll
                for (int e = 1; e < NE; e++) if (p[e] > p[i0]) i0 = e;
                int i1 = (i0 == 0) ? 1 : 0;
#pragma unroll
                for (int e = 0; e < NE; e++) if (e != i0 && p[e] > p[i1]) i1 = e;
                topk_idx[2 * t]     = i0; topk_w[2 * t]     = p[i0] * inv;
                topk_idx[2 * t + 1] = i1; topk_w[2 * t + 1] = p[i1] * inv;
                atomicAdd(&lh[i0], 1);
                atomicAdd(&lh[i1], 1);
            }
        }
        __syncthreads();
        if (tid < NE) hist_g[blockIdx.x * NE + tid] = lh[tid];
    } else {
        // ---------------- transpose body ----------------
        int tz = (int)blockIdx.x - RBLK;
        int z = tz / 352, txy = tz % 352;
        int m = z >> 3, e = z & 7;
        const float* in; unsigned short* out; int R_, C_;
        if (m == 0)      { in = w_gate; out = wg_t; R_ = HID;   C_ = INTER; }
        else if (m == 1) { in = w_up;   out = wu_t; R_ = HID;   C_ = INTER; }
        else             { in = w_down; out = wd_t; R_ = INTER; C_ = HID;   }
        int ntx = C_ >> 6;
        int bx = txy % ntx, by = txy / ntx;
        const float* ine = in + (size_t)e * R_ * C_;
        unsigned short* oute = out + (size_t)e * R_ * C_;
        int c0 = bx * 64, r0 = by * 64;
        int lr = tid >> 4;          // 0..15
        int lc = tid & 15;          // float4 column chunk
#pragma unroll
        for (int j = 0; j < 4; j++) {
            int r = lr + j * 16;
            float4 v = *(const float4*)(ine + (size_t)(r0 + r) * C_ + c0 + lc * 4);
            smem[r * 65 + lc * 4 + 0] = v.x; smem[r * 65 + lc * 4 + 1] = v.y;
            smem[r * 65 + lc * 4 + 2] = v.z; smem[r * 65 + lc * 4 + 3] = v.w;
        }
        __syncthreads();
#pragma unroll
        for (int j = 0; j < 4; j++) {
            int c = (tid >> 4) + j * 16;
            int r = (tid & 15) * 4;
            ushort4 pk;
            pk.x = f2bf(smem[(r + 0) * 65 + c]);
            pk.y = f2bf(smem[(r + 1) * 65 + c]);
            pk.z = f2bf(smem[(r + 2) * 65 + c]);
            pk.w = f2bf(smem[(r + 3) * 65 + c]);
            *(ushort4*)(oute + (size_t)(c0 + c) * R_ + r0 + r) = pk;
        }
    }
}

// ---------------------------------------------------------------- scan
__global__ __launch_bounds__(256) void moe_scan(
    const int* __restrict__ hist_g, int* __restrict__ offsets,
    int* __restrict__ block_base,
    int* __restrict__ wl256, int* __restrict__ n_wl256,
    int* __restrict__ wl64, int* __restrict__ n_wl64)
{
    __shared__ int h[RBLK * NE];
    __shared__ int cnt[NE], offs[NE];
    int tid = threadIdx.x;
    for (int i = tid; i < RBLK * NE; i += 256) h[i] = hist_g[i];
    __syncthreads();
    {
        int e = tid >> 5, g = tid & 31;
        int s = 0;
        for (int b = g; b < RBLK; b += 32) s += h[b * NE + e];
#pragma unroll
        for (int off2 = 16; off2; off2 >>= 1) s += __shfl_xor(s, off2, 32);
        if (g == 0) cnt[e] = s;
    }
    __syncthreads();
    if (tid == 0) {
        int s = 0;
        for (int e = 0; e < NE; e++) { offs[e] = s; offsets[e] = s; s += cnt[e]; }
        offsets[NE] = s;
        int n2 = 0;
        for (int e = 0; e < NE; e++)
            for (int r0 = 0; r0 < cnt[e]; r0 += 256)
                wl256[n2++] = (e << 24) | r0;
        *n_wl256 = n2;
        int n1 = 0;
        for (int e = 0; e < NE; e++)
            for (int r0 = 0; r0 < cnt[e]; r0 += 64)
                wl64[n1++] = (e << 24) | r0;
        *n_wl64 = n1;
    }
    __syncthreads();
    if (tid < NE) {
        int run = offs[tid];
        for (int b = 0; b < RBLK; b++) {
            block_base[b * NE + tid] = run;
            run += h[b * NE + tid];
        }
    }
}

// ---------------------------------------------------------------- scatter
__global__ __launch_bounds__(64) void moe_scatter(
    const int* __restrict__ topk_idx, const float* __restrict__ topk_w,
    const int* __restrict__ block_base, int* __restrict__ row_token,
    float* __restrict__ row_w, int* __restrict__ tok_rows)
{
    __shared__ int base[NE];
    int tid = threadIdx.x;
    if (tid < NE) base[tid] = block_base[blockIdx.x * NE + tid];
    __syncthreads();
    int idx = blockIdx.x * 64 + tid;     // = 2*t + k
    int e = topk_idx[idx];
    int pos = atomicAdd(&base[e], 1);    // LDS atomic
    row_token[pos] = idx >> 1;
    row_w[pos] = topk_w[idx];
    tok_rows[idx] = pos;
}

// ---------------------------------------------------------------- grouped GEMM1
// 256x256 tile, 512 threads. 4 phases/K-tile, steady gates vmcnt(4)/(6)/(4)/(6),
// final K-tile peeled with vmcnt(0)+barrier (R7 fix). Unchanged from R8.
__global__ __launch_bounds__(512, 2) void moe_gemm1(
    const unsigned short* __restrict__ xb,
    const unsigned short* __restrict__ wg_t,   // [NE][INTER][HID]
    const unsigned short* __restrict__ wu_t,   // [NE][INTER][HID]
    const int* __restrict__ offsets, const int* __restrict__ row_token,
    const int* __restrict__ wl, const int* __restrict__ n_wl,
    unsigned short* __restrict__ h_buf)        // [NROWS][INTER]
{
    if ((int)blockIdx.y >= *n_wl) return;
    int wle = wl[blockIdx.y];
    int e = wle >> 24, row0 = wle & 0xffffff;
    int off = offsets[e], cnt = offsets[e + 1] - off;
    int i0 = blockIdx.x * 128;

    __shared__ __align__(16) unsigned short As[32768];  // 64 KB: [2][2][256][32]
    __shared__ __align__(16) unsigned short Bs[32768];  // 64 KB

    int tid = threadIdx.x, wave = tid >> 6, lane = tid & 63;
    int wm = wave & 1, wn = wave >> 1;
    int l16 = lane & 15, quad = lane >> 4;
    int fsw = (l16 >> 1) & 3;                  // frag-read chunk xor

    int kswz = ((lane & 3) ^ ((lane >> 3) & 3)) * 8;
    int r0s = wave * 32 + (lane >> 2);         // staging row, load j=0
    int r1s = r0s + 16;                        // load j=1

    int gA0 = row0 + r0s, gA1 = row0 + r1s;
    int tok0 = row_token[off + ((gA0 < cnt) ? gA0 : 0)];
    int tok1 = row_token[off + ((gA1 < cnt) ? gA1 : 0)];
    const unsigned short* aptr0 = xb + (size_t)tok0 * HID + kswz;
    const unsigned short* aptr1 = xb + (size_t)tok1 * HID + kswz;

    int ic0 = i0 + (r0s >> 6) * 32 + (r0s & 31);
    int ic1 = i0 + (r1s >> 6) * 32 + (r1s & 31);
    const unsigned short* bptr0 =
        (((r0s >> 5) & 1) ? wu_t : wg_t) + (size_t)e * INTER * HID + (size_t)ic0 * HID + kswz;
    const unsigned short* bptr1 =
        (((r1s >> 5) & 1) ? wu_t : wg_t) + (size_t)e * INTER * HID + (size_t)ic1 * HID + kswz;

    f32x4 acc[8][4];
#pragma unroll
    for (int mi = 0; mi < 8; mi++)
#pragma unroll
        for (int ni = 0; ni < 4; ni++) acc[mi][ni] = {0.f, 0.f, 0.f, 0.f};

    // prologue: stage all 4 halves of K-tile 0 into buf 0, full drain once.
    {
        unsigned short* dA = &As[wave * 1024];
        unsigned short* dB = &Bs[wave * 1024];
        gl2lds16(aptr0, dA);            gl2lds16(aptr1, dA + 512);
        gl2lds16(bptr0, dB);            gl2lds16(bptr1, dB + 512);
        gl2lds16(aptr0 + 32, dA + 8192); gl2lds16(aptr1 + 32, dA + 8192 + 512);
        gl2lds16(bptr0 + 32, dB + 8192); gl2lds16(bptr1 + 32, dB + 8192 + 512);
    }
    __syncthreads();

#pragma unroll 1
    for (int kt = 0; kt < 15; kt++) {          // peeled: loop stages kt+1 always
        const unsigned short* Ac = &As[(kt & 1) << 14];
        const unsigned short* Bc = &Bs[(kt & 1) << 14];
        unsigned short* An = &As[(((kt + 1) & 1) << 14) + wave * 1024];
        unsigned short* Bn = &Bs[(((kt + 1) & 1) << 14) + wave * 1024];
        int kb = (kt + 1) * 64;
        bf16x8 a[8], b0, b1;

        // ---------- phase 1: slice 0, ni 0-1; stage A-ks0(kt+1)
        asm volatile("s_waitcnt vmcnt(4)" ::: "memory");
        __builtin_amdgcn_s_barrier();
#pragma unroll
        for (int mi = 0; mi < 8; mi++)
            a[mi] = *(const bf16x8*)&Ac[(wm * 128 + mi * 16 + l16) * 32 + (quad ^ fsw) * 8];
        b0 = *(const bf16x8*)&Bc[(wn * 64 + l16) * 32 + (quad ^ fsw) * 8];
        b1 = *(const bf16x8*)&Bc[(wn * 64 + 16 + l16) * 32 + (quad ^ fsw) * 8];
        gl2lds16(aptr0 + kb, An); gl2lds16(aptr1 + kb, An + 512);
        __builtin_amdgcn_s_setprio(1);
#pragma unroll
        for (int mi = 0; mi < 8; mi++) {
            acc[mi][0] = __builtin_amdgcn_mfma_f32_16x16x32_bf16(a[mi], b0, acc[mi][0], 0, 0, 0);
            acc[mi][1] = __builtin_amdgcn_mfma_f32_16x16x32_bf16(a[mi], b1, acc[mi][1], 0, 0, 0);
        }
        __builtin_amdgcn_s_setprio(0);

        // ---------- phase 2: slice 0, ni 2-3; stage B-ks0(kt+1)
        asm volatile("s_waitcnt vmcnt(6)" ::: "memory");
        __builtin_amdgcn_s_barrier();
        b0 = *(const bf16x8*)&Bc[(wn * 64 + 32 + l16) * 32 + (quad ^ fsw) * 8];
        b1 = *(const bf16x8*)&Bc[(wn * 64 + 48 + l16) * 32 + (quad ^ fsw) * 8];
        gl2lds16(bptr0 + kb, Bn); gl2lds16(bptr1 + kb, Bn + 512);
        __builtin_amdgcn_s_setprio(1);
#pragma unroll
        for (int mi = 0; mi < 8; mi++) {
            acc[mi][2] = __builtin_amdgcn_mfma_f32_16x16x32_bf16(a[mi], b0, acc[mi][2], 0, 0, 0);
            acc[mi][3] = __builtin_amdgcn_mfma_f32_16x16x32_bf16(a[mi], b1, acc[mi][3], 0, 0, 0);
        }
        __builtin_amdgcn_s_setprio(0);

        // ---------- phase 3: slice 1, ni 0-1; stage A-ks1(kt+1)
        asm volatile("s_waitcnt vmcnt(4)" ::: "memory");
        __builtin_amdgcn_s_barrier();
#pragma unroll
        for (int mi = 0; mi < 8; mi++)
            a[mi] = *(const bf16x8*)&Ac[8192 + (wm * 128 + mi * 16 + l16) * 32 + (quad ^ fsw) * 8];
        b0 = *(const bf16x8*)&Bc[8192 + (wn * 64 + l16) * 32 + (quad ^ fsw) * 8];
        b1 = *(const bf16x8*)&Bc[8192 + (wn * 64 + 16 + l16) * 32 + (quad ^ fsw) * 8];
        gl2lds16(aptr0 + kb + 32, An + 8192); gl2lds16(aptr1 + kb + 32, An + 8192 + 512);
        __builtin_amdgcn_s_setprio(1);
#pragma unroll
        for (int mi = 0; mi < 8; mi++) {
            acc[mi][0] = __builtin_amdgcn_mfma_f32_16x16x32_bf16(a[mi], b0, acc[mi][0], 0, 0, 0);
            acc[mi][1] = __builtin_amdgcn_mfma_f32_16x16x32_bf16(a[mi], b1, acc[mi][1], 0, 0, 0);
        }
        __builtin_amdgcn_s_setprio(0);

        // ---------- phase 4: slice 1, ni 2-3; stage B-ks1(kt+1)
        asm volatile("s_waitcnt vmcnt(6)" ::: "memory");
        __builtin_amdgcn_s_barrier();
        b0 = *(const bf16x8*)&Bc[8192 + (wn * 64 + 32 + l16) * 32 + (quad ^ fsw) * 8];
        b1 = *(const bf16x8*)&Bc[8192 + (wn * 64 + 48 + l16) * 32 + (quad ^ fsw) * 8];
        gl2lds16(bptr0 + kb + 32, Bn + 8192); gl2lds16(bptr1 + kb + 32, Bn + 8192 + 512);
        __builtin_amdgcn_s_setprio(1);
#pragma unroll
        for (int mi = 0; mi < 8; mi++) {
            acc[mi][2] = __builtin_amdgcn_mfma_f32_16x16x32_bf16(a[mi], b0, acc[mi][2], 0, 0, 0);
            acc[mi][3] = __builtin_amdgcn_mfma_f32_16x16x32_bf16(a[mi], b1, acc[mi][3], 0, 0, 0);
        }
        __builtin_amdgcn_s_setprio(0);
    }

    // ---------- peeled tail: K-tile 15 (buf 1), full drain, no staging.
    {
        const unsigned short* Ac = &As[1 << 14];
        const unsigned short* Bc = &Bs[1 << 14];
        asm volatile("s_waitcnt vmcnt(0)" ::: "memory");
        __builtin_amdgcn_s_barrier();
        bf16x8 a[8], b0, b1;
#pragma unroll
        for (int sl = 0; sl < 2; sl++) {
            int so = sl * 8192;
#pragma unroll
            for (int mi = 0; mi < 8; mi++)
                a[mi] = *(const bf16x8*)&Ac[so + (wm * 128 + mi * 16 + l16) * 32 + (quad ^ fsw) * 8];
            b0 = *(const bf16x8*)&Bc[so + (wn * 64 + l16) * 32 + (quad ^ fsw) * 8];
            b1 = *(const bf16x8*)&Bc[so + (wn * 64 + 16 + l16) * 32 + (quad ^ fsw) * 8];
#pragma unroll
            for (int mi = 0; mi < 8; mi++) {
                acc[mi][0] = __builtin_amdgcn_mfma_f32_16x16x32_bf16(a[mi], b0, acc[mi][0], 0, 0, 0);
                acc[mi][1] = __builtin_amdgcn_mfma_f32_16x16x32_bf16(a[mi], b1, acc[mi][1], 0, 0, 0);
            }
            b0 = *(const bf16x8*)&Bc[so + (wn * 64 + 32 + l16) * 32 + (quad ^ fsw) * 8];
            b1 = *(const bf16x8*)&Bc[so + (wn * 64 + 48 + l16) * 32 + (quad ^ fsw) * 8];
#pragma unroll
            for (int mi = 0; mi < 8; mi++) {
                acc[mi][2] = __builtin_amdgcn_mfma_f32_16x16x32_bf16(a[mi], b0, acc[mi][2], 0, 0, 0);
                acc[mi][3] = __builtin_amdgcn_mfma_f32_16x16x32_bf16(a[mi], b1, acc[mi][3], 0, 0, 0);
            }
        }
    }

    // epilogue: silu(g)*u -> bf16  (C/D: col=lane&15, row=quad*4+reg)
#pragma unroll
    for (int mi = 0; mi < 8; mi++)
#pragma unroll
        for (int np = 0; np < 2; np++)
#pragma unroll
            for (int r = 0; r < 4; r++) {
                int ml = wm * 128 + mi * 16 + quad * 4 + r;
                int row = row0 + ml;
                if (row < cnt) {
                    float g = acc[mi][np][r], u = acc[mi][np + 2][r];
                    float hv = (g / (1.f + expf(-g))) * u;
                    h_buf[(size_t)(off + row) * INTER + i0 + wn * 32 + np * 16 + l16] = f2bf(hv);
                }
            }
}

// ---------------------------------------------------------------- grouped GEMM2
// 64x128 tile, 256 threads (4 waves 1M x 4N; per-wave 64x32). LDS 48 KB ->
// 3 blocks/CU: ~2056 blocks over 768 slots = 2.68 rounds with a small tail
// (R8's 128x128 at 2/CU was 544/512 = 1.06 dual-rounds -> ~half the kernel
// was a 32-block tail). 2 phases/K-tile (one 32-K slice each); per phase
// stage next tile's same slice: A x1 + B x2 = 3 loads. Gate: 6 outstanding
// at each steady gate, need oldest 3 -> vmcnt(3). Final K-tile peeled with
// vmcnt(0)+barrier (R7 tail-race fix).
__global__ __launch_bounds__(256, 3) void moe_gemm2(
    const unsigned short* __restrict__ h_buf,  // [NROWS][INTER]
    const unsigned short* __restrict__ wd_t,   // [NE][HID][INTER]
    const int* __restrict__ offsets, const float* __restrict__ row_w,
    const int* __restrict__ wl, const int* __restrict__ n_wl,
    unsigned short* __restrict__ y_buf)        // [NROWS][HID]
{
    if ((int)blockIdx.y >= *n_wl) return;
    int wle = wl[blockIdx.y];
    int e = wle >> 24, row0 = wle & 0xffffff;
    int off = offsets[e], cnt = offsets[e + 1] - off;
    int h0 = blockIdx.x * 128;

    __shared__ __align__(16) unsigned short As[8192];   // 16 KB: [2][2][64][32]
    __shared__ __align__(16) unsigned short Bs[16384];  // 32 KB: [2][2][128][32]

    int tid = threadIdx.x, wave = tid >> 6, lane = tid & 63;
    int wn = wave;                            // 1M x 4N
    int l16 = lane & 15, quad = lane >> 4;
    int fsw = (l16 >> 1) & 3;

    int kswz = ((lane & 3) ^ ((lane >> 3) & 3)) * 8;
    int rs = wave * 16 + (lane >> 2);         // staging row 0..63

    int gA = row0 + rs;
    const unsigned short* aptr  = h_buf + (size_t)(off + ((gA < cnt) ? gA : 0)) * INTER + kswz;
    const unsigned short* bptr0 = wd_t + (size_t)e * HID * INTER + (size_t)(h0 + rs) * INTER + kswz;
    const unsigned short* bptr1 = wd_t + (size_t)e * HID * INTER + (size_t)(h0 + rs + 64) * INTER + kswz;

    f32x4 acc[4][2];
#pragma unroll
    for (int mi = 0; mi < 4; mi++)
#pragma unroll
        for (int ni = 0; ni < 2; ni++) acc[mi][ni] = {0.f, 0.f, 0.f, 0.f};

    // prologue: stage both slices of K-tile 0 into buf 0 (6 loads), full drain.
    // LDS elem layout: A buf*4096 + slice*2048 + row*32 + chunk*8;
    //                  B buf*8192 + slice*4096 + row*32 + chunk*8.
    {
        unsigned short* dA = &As[wave * 512];
        unsigned short* dB = &Bs[wave * 512];
        gl2lds16(aptr, dA);
        gl2lds16(bptr0, dB);             gl2lds16(bptr1, dB + 2048);
        gl2lds16(aptr + 32, dA + 2048);
        gl2lds16(bptr0 + 32, dB + 4096); gl2lds16(bptr1 + 32, dB + 4096 + 2048);
    }
    __syncthreads();

#pragma unroll 1
    for (int kt = 0; kt < 21; kt++) {          // peeled: loop stages kt+1 always
        const unsigned short* Ac = &As[(kt & 1) << 12];
        const unsigned short* Bc = &Bs[(kt & 1) << 13];
        unsigned short* An = &As[(((kt + 1) & 1) << 12) + wave * 512];
        unsigned short* Bn = &Bs[(((kt + 1) & 1) << 13) + wave * 512];
        int kb = (kt + 1) * 64;
        bf16x8 a[4], b0, b1;

        // ---------- phase 1: slice 0; stage slice-0(kt+1): A x1 + B x2
        asm volatile("s_waitcnt vmcnt(3)" ::: "memory");
        __builtin_amdgcn_s_barrier();
#pragma unroll
        for (int mi = 0; mi < 4; mi++)
            a[mi] = *(const bf16x8*)&Ac[(mi * 16 + l16) * 32 + (quad ^ fsw) * 8];
        b0 = *(const bf16x8*)&Bc[(wn * 32 + l16) * 32 + (quad ^ fsw) * 8];
        b1 = *(const bf16x8*)&Bc[(wn * 32 + 16 + l16) * 32 + (quad ^ fsw) * 8];
        gl2lds16(aptr + kb, An);
        gl2lds16(bptr0 + kb, Bn); gl2lds16(bptr1 + kb, Bn + 2048);
        __builtin_amdgcn_s_setprio(1);
#pragma unroll
        for (int mi = 0; mi < 4; mi++) {
            acc[mi][0] = __builtin_amdgcn_mfma_f32_16x16x32_bf16(a[mi], b0, acc[mi][0], 0, 0, 0);
            acc[mi][1] = __builtin_amdgcn_mfma_f32_16x16x32_bf16(a[mi], b1, acc[mi][1], 0, 0, 0);
        }
        __builtin_amdgcn_s_setprio(0);

        // ---------- phase 2: slice 1; stage slice-1(kt+1): A x1 + B x2
        asm volatile("s_waitcnt vmcnt(3)" ::: "memory");
        __builtin_amdgcn_s_barrier();
#pragma unroll
        for (int mi = 0; mi < 4; mi++)
            a[mi] = *(const bf16x8*)&Ac[2048 + (mi * 16 + l16) * 32 + (quad ^ fsw) * 8];
        b0 = *(const bf16x8*)&Bc[4096 + (wn * 32 + l16) * 32 + (quad ^ fsw) * 8];
        b1 = *(const bf16x8*)&Bc[4096 + (wn * 32 + 16 + l16) * 32 + (quad ^ fsw) * 8];
        gl2lds16(aptr + kb + 32, An + 2048);
        gl2lds16(bptr0 + kb + 32, Bn + 4096); gl2lds16(bptr1 + kb + 32, Bn + 4096 + 2048);
        __builtin_amdgcn_s_setprio(1);
#pragma unroll
        for (int mi = 0; mi < 4; mi++) {
            acc[mi][0] = __builtin_amdgcn_mfma_f32_16x16x32_bf16(a[mi], b0, acc[mi][0], 0, 0, 0);
            acc[mi][1] = __builtin_amdgcn_mfma_f32_16x16x32_bf16(a[mi], b1, acc[mi][1], 0, 0, 0);
        }
        __builtin_amdgcn_s_setprio(0);
    }

    // ---------- peeled tail: K-tile 21 (buf 1), full drain, no staging.
    {
        const unsigned short* Ac = &As[1 << 12];
        const unsigned short* Bc = &Bs[1 << 13];
        asm volatile("s_waitcnt vmcnt(0)" ::: "memory");
        __builtin_amdgcn_s_barrier();
        bf16x8 a[4], b0, b1;
#pragma unroll
        for (int sl = 0; sl < 2; sl++) {
            int soA = sl * 2048, soB = sl * 4096;
#pragma unroll
            for (int mi = 0; mi < 4; mi++)
                a[mi] = *(const bf16x8*)&Ac[soA + (mi * 16 + l16) * 32 + (quad ^ fsw) * 8];
            b0 = *(const bf16x8*)&Bc[soB + (wn * 32 + l16) * 32 + (quad ^ fsw) * 8];
            b1 = *(const bf16x8*)&Bc[soB + (wn * 32 + 16 + l16) * 32 + (quad ^ fsw) * 8];
#pragma unroll
            for (int mi = 0; mi < 4; mi++) {
                acc[mi][0] = __builtin_amdgcn_mfma_f32_16x16x32_bf16(a[mi], b0, acc[mi][0], 0, 0, 0);
                acc[mi][1] = __builtin_amdgcn_mfma_f32_16x16x32_bf16(a[mi], b1, acc[mi][1], 0, 0, 0);
            }
        }
    }

    // epilogue: scale by row_w -> bf16  (C/D: col=lane&15, row=quad*4+reg)
#pragma unroll
    for (int mi = 0; mi < 4; mi++)
#pragma unroll
        for (int ni = 0; ni < 2; ni++)
#pragma unroll
            for (int r = 0; r < 4; r++) {
                int ml = mi * 16 + quad * 4 + r;
                int row = row0 + ml;
                if (row < cnt) {
                    float w = row_w[off + row];
                    y_buf[(size_t)(off + row) * HID + h0 + wn * 32 + ni * 16 + l16] =
                        f2bf(acc[mi][ni][r] * w);
                }
            }
}

// ---------------------------------------------------------------- combine
__global__ __launch_bounds__(256) void moe_combine(
    const unsigned short* __restrict__ y_buf, const int* __restrict__ tok_rows,
    float* __restrict__ out)
{
    int gid = blockIdx.x * 256 + threadIdx.x;   // T*H/8 threads
    int t = gid >> 7;
    int c = gid & 127;
    u32x4 a = *(const u32x4*)(y_buf + (size_t)tok_rows[2 * t]     * HID + c * 8);
    u32x4 b = *(const u32x4*)(y_buf + (size_t)tok_rows[2 * t + 1] * HID + c * 8);
    float res[8];
#pragma unroll
    for (int j = 0; j < 4; j++) {
        unsigned int wa = a[j], wb = b[j];
        res[2 * j]     = __builtin_bit_cast(float, wa << 16)
                       + __builtin_bit_cast(float, wb << 16);
        res[2 * j + 1] = __builtin_bit_cast(float, wa & 0xffff0000u)
                       + __builtin_bit_cast(float, wb & 0xffff0000u);
    }
    float* o = out + (size_t)t * HID + c * 8;
    *(float4*)(o)     = make_float4(res[0], res[1], res[2], res[3]);
    *(float4*)(o + 4) = make_float4(res[4], res[5], res[6], res[7]);
}

// ---------------------------------------------------------------- launch
extern "C" void kernel_launch(void* const* d_in, const int* in_sizes, int n_in,
                              void* d_out, int out_size, void* d_ws, size_t ws_size,
                              hipStream_t stream)
{
    const float* x      = (const float*)d_in[0];
    const float* gate_w = (const float*)d_in[1];
    const float* w_gate = (const float*)d_in[2];
    const float* w_up   = (const float*)d_in[3];
    const float* w_down = (const float*)d_in[4];
    float* out = (float*)d_out;                    // final [T,H] ++ logits [T,E]
    float* logits_out = out + (size_t)T_TOK * HID;

    char* ws = (char*)d_ws;
    int*   offsets    = (int*)(ws + 0);                  // 9 ints
    int*   n_wl256    = (int*)(ws + 64);
    int*   n_wl64     = (int*)(ws + 68);
    int*   wl256      = (int*)(ws + 128);                // 72 ints
    int*   wl64       = (int*)(ws + 512);                // 264 ints
    int*   hist_g     = (int*)(ws + 2048);               // RBLK*NE = 8 KB
    int*   block_base = (int*)(ws + 2048 + 8192);        // 8 KB
    int*   topk_idx   = (int*)(ws + 32768);                       // 64 KB
    float* topk_w     = (float*)(ws + 32768 + 65536);             // 64 KB
    int*   row_token  = (int*)(ws + 32768 + 2 * 65536);           // 64 KB
    float* row_w      = (float*)(ws + 32768 + 3 * 65536);         // 64 KB
    int*   tok_rows   = (int*)(ws + 32768 + 4 * 65536);           // 64 KB
    size_t o = 32768 + 5 * (size_t)65536 + 32768;        // 393216
    unsigned short* xb   = (unsigned short*)(ws + o); o += (size_t)T_TOK * HID * 2;
    unsigned short* wg_t = (unsigned short*)(ws + o); o += (size_t)NE * INTER * HID * 2;
    unsigned short* wu_t = (unsigned short*)(ws + o); o += (size_t)NE * INTER * HID * 2;
    unsigned short* wd_t = (unsigned short*)(ws + o); o += (size_t)NE * HID * INTER * 2;
    unsigned short* h_buf = (unsigned short*)(ws + o); o += (size_t)NROWS * INTER * 2;
    unsigned short* y_buf = (unsigned short*)(ws + o); o += (size_t)NROWS * HID * 2;

    moe_pre<<<RBLK + NTRT, 256, 0, stream>>>(
        x, gate_w, w_gate, w_up, w_down,
        xb, logits_out, topk_idx, topk_w, hist_g, wg_t, wu_t, wd_t);
    moe_scan<<<1, 256, 0, stream>>>(hist_g, offsets, block_base,
                                    wl256, n_wl256, wl64, n_wl64);
    moe_scatter<<<RBLK, 64, 0, stream>>>(topk_idx, topk_w, block_base,
                                         row_token, row_w, tok_rows);

    moe_gemm1<<<dim3(GX1, MAXWL256), 512, 0, stream>>>(
        xb, wg_t, wu_t, offsets, row_token, wl256, n_wl256, h_buf);
    moe_gemm2<<<dim3(GX2, MAXWL64), 256, 0, stream>>>(
        h_buf, wd_t, offsets, row_w, wl64, n_wl64, y_buf);
    moe_combine<<<(T_TOK * HID / 8) / 256, 256, 0, stream>>>(y_buf, tok_rows, out);
}